// Round 1
// baseline (10993.387 us; speedup 1.0000x reference)
//
#include <hip/hip_runtime.h>

typedef _Float16 half8 __attribute__((ext_vector_type(8)));
typedef _Float16 half4v __attribute__((ext_vector_type(4)));
typedef float float4v __attribute__((ext_vector_type(4)));

#define HID 2048
#define EMBD 2048
#define BATCH 128
#define TSTEPS 256

// ---------------- small prep kernels ----------------
__global__ __launch_bounds__(256) void cast_f16_kernel(const float* __restrict__ src,
                                                       _Float16* __restrict__ dst, int n) {
    int i = (blockIdx.x * 256 + threadIdx.x) * 4;
    int stride = gridDim.x * 256 * 4;
    for (; i < n; i += stride) {
        float4v v = *(const float4v*)(src + i);
        half4v h;
        h[0] = (_Float16)v[0]; h[1] = (_Float16)v[1];
        h[2] = (_Float16)v[2]; h[3] = (_Float16)v[3];
        *(half4v*)(dst + i) = h;
    }
}

__global__ __launch_bounds__(256) void bias_kernel(const float* __restrict__ a,
                                                   const float* __restrict__ b,
                                                   float* __restrict__ dst) {
    int i = blockIdx.x * 256 + threadIdx.x;
    if (i < HID) dst[i] = a[i] + b[i];
}

// ---------------- Phase A: xproj = gather(emb,x) @ W_ih^T + bias ----------------
// M = T*B = 32768 (tile 128 = one t), N = 2048 (tile 128), K = 2048 (BK=64)
__global__ __launch_bounds__(256) void phaseA_kernel(const int* __restrict__ x,
                                                     const float* __restrict__ emb,
                                                     const _Float16* __restrict__ w16,
                                                     const float* __restrict__ bias,
                                                     _Float16* __restrict__ xproj) {
    __shared__ __align__(16) _Float16 As[128 * 64];
    __shared__ __align__(16) _Float16 Bs[128 * 64];

    const int tid = threadIdx.x;
    const int bx  = blockIdx.x;
    const int nt = bx & 15, mt = bx >> 4;      // nt fast: concurrent blocks share A-rows
    const long m0 = (long)mt * 128;
    const long n0 = (long)nt * 128;
    const int lane = tid & 63, w = tid >> 6;
    const int ln15 = lane & 15, kg = lane >> 4;
    const int wr = (w >> 1) * 64, wc = (w & 1) * 64;

    // token row ids for the 4 staging chunks this thread handles
    int xr[4];
#pragma unroll
    for (int it = 0; it < 4; ++it) xr[it] = x[m0 + ((it * 256 + tid) >> 3)];

    float4v acc[4][4];
#pragma unroll
    for (int m = 0; m < 4; ++m)
#pragma unroll
        for (int n = 0; n < 4; ++n) acc[m][n] = (float4v){0.f, 0.f, 0.f, 0.f};

    for (int kt = 0; kt < 32; ++kt) {
        __syncthreads();
        // stage A: gather emb rows, f32 -> f16
#pragma unroll
        for (int it = 0; it < 4; ++it) {
            int c = it * 256 + tid;
            const float* src = emb + (long)xr[it] * EMBD + kt * 64 + (c & 7) * 8;
            float4v v0 = *(const float4v*)src;
            float4v v1 = *(const float4v*)(src + 4);
            half8 hv;
#pragma unroll
            for (int q = 0; q < 4; ++q) { hv[q] = (_Float16)v0[q]; hv[4 + q] = (_Float16)v1[q]; }
            *(half8*)(&As[c * 8]) = hv;
        }
        // stage B: W_ih fp16 rows [n][k]
#pragma unroll
        for (int it = 0; it < 4; ++it) {
            int c = it * 256 + tid;
            const _Float16* src = w16 + (n0 + (c >> 3)) * (long)EMBD + kt * 64 + (c & 7) * 8;
            *(half8*)(&Bs[c * 8]) = *(const half8*)src;
        }
        __syncthreads();
#pragma unroll
        for (int kk = 0; kk < 2; ++kk) {
            half8 a[4], b[4];
#pragma unroll
            for (int m = 0; m < 4; ++m)
                a[m] = *(half8*)(&As[(wr + m * 16 + ln15) * 64 + kk * 32 + kg * 8]);
#pragma unroll
            for (int n = 0; n < 4; ++n)
                b[n] = *(half8*)(&Bs[(wc + n * 16 + ln15) * 64 + kk * 32 + kg * 8]);
#pragma unroll
            for (int m = 0; m < 4; ++m)
#pragma unroll
                for (int n = 0; n < 4; ++n)
                    acc[m][n] = __builtin_amdgcn_mfma_f32_16x16x32_f16(a[m], b[n], acc[m][n], 0, 0, 0);
        }
    }
    // epilogue: C/D layout col=lane&15, row=(lane>>4)*4+reg  [m89-verified]
#pragma unroll
    for (int n = 0; n < 4; ++n) {
        int j = wc + n * 16 + ln15;
        float bv = bias[n0 + j];
#pragma unroll
        for (int m = 0; m < 4; ++m)
#pragma unroll
            for (int r = 0; r < 4; ++r) {
                int i = wr + m * 16 + kg * 4 + r;
                xproj[(m0 + i) * (long)HID + n0 + j] = (_Float16)(acc[m][n][r] + bv);
            }
    }
}

// ---------------- Phase B: persistent cooperative scan ----------------
// 256 blocks: 4 m-tiles (32 rows) x 64 n-tiles (32 cols). W slice in registers.
__global__ __launch_bounds__(256, 1) void scan_kernel(const _Float16* __restrict__ xproj,
                                                      const _Float16* __restrict__ whh,
                                                      _Float16* __restrict__ hA,
                                                      _Float16* __restrict__ hB,
                                                      float* __restrict__ hlast,
                                                      unsigned* __restrict__ cnt) {
    __shared__ __align__(16) float part[4 * 32 * 32];

    const int tid = threadIdx.x;
    const int bx = blockIdx.x;
    const int mt = bx & 3, nt = bx >> 2;
    const int m0 = mt * 32, n0 = nt * 32;
    const int lane = tid & 63, w = tid >> 6;
    const int ln15 = lane & 15, kg = lane >> 4;
    const int kbase = w * 512;  // per-wave K slice

    // preload W_hh slice into registers: wreg[nf][ki] = W[n0+nf*16+ln15][kbase+ki*32+kg*8 ..+7]
    half8 wreg[2][16];
#pragma unroll
    for (int nf = 0; nf < 2; ++nf) {
        long n = n0 + nf * 16 + ln15;
#pragma unroll
        for (int ki = 0; ki < 16; ++ki)
            wreg[nf][ki] = *(const half8*)(whh + n * HID + kbase + ki * 32 + kg * 8);
    }

    const int brow = tid >> 3, ng = tid & 7;  // reduce-phase mapping

    for (int t = 0; t < TSTEPS; ++t) {
        const _Float16* hcur = (t & 1) ? hB : hA;
        _Float16* hnext = (t & 1) ? hA : hB;

        float4v acc[2][2];
#pragma unroll
        for (int mf = 0; mf < 2; ++mf)
#pragma unroll
            for (int nf = 0; nf < 2; ++nf) acc[mf][nf] = (float4v){0.f, 0.f, 0.f, 0.f};

#pragma unroll
        for (int ki = 0; ki < 16; ++ki) {
            half8 a0 = *(const half8*)(hcur + (long)(m0 + ln15) * HID + kbase + ki * 32 + kg * 8);
            half8 a1 = *(const half8*)(hcur + (long)(m0 + 16 + ln15) * HID + kbase + ki * 32 + kg * 8);
            acc[0][0] = __builtin_amdgcn_mfma_f32_16x16x32_f16(a0, wreg[0][ki], acc[0][0], 0, 0, 0);
            acc[0][1] = __builtin_amdgcn_mfma_f32_16x16x32_f16(a0, wreg[1][ki], acc[0][1], 0, 0, 0);
            acc[1][0] = __builtin_amdgcn_mfma_f32_16x16x32_f16(a1, wreg[0][ki], acc[1][0], 0, 0, 0);
            acc[1][1] = __builtin_amdgcn_mfma_f32_16x16x32_f16(a1, wreg[1][ki], acc[1][1], 0, 0, 0);
        }

        // partial store to LDS, XOR-swizzled to dodge bank conflicts
#pragma unroll
        for (int mf = 0; mf < 2; ++mf)
#pragma unroll
            for (int nf = 0; nf < 2; ++nf)
#pragma unroll
                for (int r = 0; r < 4; ++r) {
                    int i = mf * 16 + kg * 4 + r, j = nf * 16 + ln15;
                    int byte = (w * 4096 + i * 128 + j * 4) ^ ((i & 7) << 4);
                    *(float*)((char*)part + byte) = acc[mf][nf][r];
                }
        __syncthreads();

        // cross-wave reduce + xp + tanh + store
        float4v s = (float4v){0.f, 0.f, 0.f, 0.f};
#pragma unroll
        for (int ww = 0; ww < 4; ++ww) {
            int byte = (ww * 4096 + brow * 128 + ng * 16) ^ ((brow & 7) << 4);
            float4v p = *(float4v*)((char*)part + byte);
            s = s + p;
        }
        long xoff = (long)t * BATCH * HID + (long)(m0 + brow) * HID + n0 + ng * 4;
        half4v xpv = *(const half4v*)(xproj + xoff);
        float o0 = tanhf((float)xpv[0] + s[0]);
        float o1 = tanhf((float)xpv[1] + s[1]);
        float o2 = tanhf((float)xpv[2] + s[2]);
        float o3 = tanhf((float)xpv[3] + s[3]);
        half4v hv; hv[0] = (_Float16)o0; hv[1] = (_Float16)o1; hv[2] = (_Float16)o2; hv[3] = (_Float16)o3;
        long hoff = (long)(m0 + brow) * HID + n0 + ng * 4;
        *(half4v*)(hnext + hoff) = hv;
        if (t == TSTEPS - 1) {
            float4v f = {o0, o1, o2, o3};
            *(float4v*)(hlast + hoff) = f;
        }

        // grid barrier (monotonic counter; device-scope for cross-XCD visibility)
        __syncthreads();
        if (tid == 0) {
            __threadfence();
            __hip_atomic_fetch_add(cnt, 1u, __ATOMIC_RELEASE, __HIP_MEMORY_SCOPE_AGENT);
            unsigned target = (unsigned)(t + 1) * 256u;
            while (__hip_atomic_load(cnt, __ATOMIC_ACQUIRE, __HIP_MEMORY_SCOPE_AGENT) < target)
                __builtin_amdgcn_s_sleep(2);
        }
        __syncthreads();
        __threadfence();
    }
}

// ---------------- head ----------------
__global__ __launch_bounds__(256) void fc1_kernel(const float* __restrict__ hlast,
                                                  const float* __restrict__ w,
                                                  const float* __restrict__ b,
                                                  float* __restrict__ z) {
    int bb = blockIdx.x;
    int j = threadIdx.x;
    const float* hr = hlast + (long)bb * HID;
    const float* wr = w + (long)j * HID;
    float acc = 0.f;
    for (int k = 0; k < HID; k += 4) {
        float4v hv = *(const float4v*)(hr + k);
        float4v wv = *(const float4v*)(wr + k);
        acc += hv[0] * wv[0] + hv[1] * wv[1] + hv[2] * wv[2] + hv[3] * wv[3];
    }
    acc += b[j];
    z[bb * 256 + j] = fmaxf(acc, 0.f);
}

__global__ __launch_bounds__(256) void fc2_kernel(const float* __restrict__ z,
                                                  const float* __restrict__ w,
                                                  const float* __restrict__ b,
                                                  float* __restrict__ out) {
    __shared__ float red[4];
    int bb = blockIdx.x;
    int tid = threadIdx.x;
    float zv = z[bb * 256 + tid];
    for (int c = 0; c < 3; ++c) {
        float s = zv * w[c * 256 + tid];
        for (int off = 32; off > 0; off >>= 1) s += __shfl_down(s, off, 64);
        if ((tid & 63) == 0) red[tid >> 6] = s;
        __syncthreads();
        if (tid == 0) out[bb * 3 + c] = red[0] + red[1] + red[2] + red[3] + b[c];
        __syncthreads();
    }
}

// ---------------- launch ----------------
extern "C" void kernel_launch(void* const* d_in, const int* in_sizes, int n_in,
                              void* d_out, int out_size, void* d_ws, size_t ws_size,
                              hipStream_t stream) {
    const int*   x    = (const int*)d_in[0];
    const float* emb  = (const float*)d_in[1];
    const float* Wih  = (const float*)d_in[2];
    const float* Whh  = (const float*)d_in[3];
    const float* bih  = (const float*)d_in[4];
    const float* bhh  = (const float*)d_in[5];
    const float* fc1w = (const float*)d_in[6];
    const float* fc1b = (const float*)d_in[7];
    const float* fc2w = (const float*)d_in[8];
    const float* fc2b = (const float*)d_in[9];
    float* out = (float*)d_out;

    char* ws = (char*)d_ws;
    size_t off = 0;
    _Float16* xproj = (_Float16*)(ws + off); off += (size_t)TSTEPS * BATCH * HID * 2;  // 134.2 MB
    _Float16* wih16 = (_Float16*)(ws + off); off += (size_t)HID * EMBD * 2;            // 8 MB
    _Float16* whh16 = (_Float16*)(ws + off); off += (size_t)HID * HID * 2;             // 8 MB
    float*    bias  = (float*)(ws + off);    off += (size_t)HID * 4;
    _Float16* hA    = (_Float16*)(ws + off); off += (size_t)BATCH * HID * 2;
    _Float16* hB    = (_Float16*)(ws + off); off += (size_t)BATCH * HID * 2;
    float*    hlast = (float*)(ws + off);    off += (size_t)BATCH * HID * 4;
    float*    z     = (float*)(ws + off);    off += (size_t)BATCH * 256 * 4;
    unsigned* cnt   = (unsigned*)(ws + off); off += 128;

    hipMemsetAsync(cnt, 0, 128, stream);
    hipMemsetAsync(hA, 0, (size_t)BATCH * HID * 2, stream);

    cast_f16_kernel<<<4096, 256, 0, stream>>>(Wih, wih16, HID * EMBD);
    cast_f16_kernel<<<4096, 256, 0, stream>>>(Whh, whh16, HID * HID);
    bias_kernel<<<8, 256, 0, stream>>>(bih, bhh, bias);

    phaseA_kernel<<<4096, 256, 0, stream>>>(x, emb, wih16, bias, xproj);

    void* args[] = {(void*)&xproj, (void*)&whh16, (void*)&hA, (void*)&hB, (void*)&hlast, (void*)&cnt};
    hipLaunchCooperativeKernel((const void*)scan_kernel, dim3(256), dim3(256), args, 0, stream);

    fc1_kernel<<<BATCH, 256, 0, stream>>>(hlast, fc1w, fc1b, z);
    fc2_kernel<<<BATCH, 256, 0, stream>>>(z, fc2w, fc2b, out);
}

// Round 2
// 5085.022 us; speedup vs baseline: 2.1619x; 2.1619x over previous
//
#include <hip/hip_runtime.h>

typedef _Float16 half8 __attribute__((ext_vector_type(8)));
typedef _Float16 half4v __attribute__((ext_vector_type(4)));
typedef float float4v __attribute__((ext_vector_type(4)));

#define HID 2048
#define EMBD 2048
#define BATCH 128
#define TSTEPS 256

// ---------------- small prep kernels ----------------
__global__ __launch_bounds__(256) void cast_f16_kernel(const float* __restrict__ src,
                                                       _Float16* __restrict__ dst, int n) {
    int i = (blockIdx.x * 256 + threadIdx.x) * 4;
    int stride = gridDim.x * 256 * 4;
    for (; i < n; i += stride) {
        float4v v = *(const float4v*)(src + i);
        half4v h;
        h[0] = (_Float16)v[0]; h[1] = (_Float16)v[1];
        h[2] = (_Float16)v[2]; h[3] = (_Float16)v[3];
        *(half4v*)(dst + i) = h;
    }
}

__global__ __launch_bounds__(256) void bias_kernel(const float* __restrict__ a,
                                                   const float* __restrict__ b,
                                                   float* __restrict__ dst) {
    int i = blockIdx.x * 256 + threadIdx.x;
    if (i < HID) dst[i] = a[i] + b[i];
}

// ---------------- Phase A: xproj = gather(emb,x) @ W_ih^T + bias ----------------
__global__ __launch_bounds__(256) void phaseA_kernel(const int* __restrict__ x,
                                                     const float* __restrict__ emb,
                                                     const _Float16* __restrict__ w16,
                                                     const float* __restrict__ bias,
                                                     _Float16* __restrict__ xproj) {
    __shared__ __align__(16) _Float16 As[128 * 64];
    __shared__ __align__(16) _Float16 Bs[128 * 64];

    const int tid = threadIdx.x;
    const int bx  = blockIdx.x;
    const int nt = bx & 15, mt = bx >> 4;
    const long m0 = (long)mt * 128;
    const long n0 = (long)nt * 128;
    const int lane = tid & 63, w = tid >> 6;
    const int ln15 = lane & 15, kg = lane >> 4;
    const int wr = (w >> 1) * 64, wc = (w & 1) * 64;

    int xr[4];
#pragma unroll
    for (int it = 0; it < 4; ++it) xr[it] = x[m0 + ((it * 256 + tid) >> 3)];

    float4v acc[4][4];
#pragma unroll
    for (int m = 0; m < 4; ++m)
#pragma unroll
        for (int n = 0; n < 4; ++n) acc[m][n] = (float4v){0.f, 0.f, 0.f, 0.f};

    for (int kt = 0; kt < 32; ++kt) {
        __syncthreads();
#pragma unroll
        for (int it = 0; it < 4; ++it) {
            int c = it * 256 + tid;
            const float* src = emb + (long)xr[it] * EMBD + kt * 64 + (c & 7) * 8;
            float4v v0 = *(const float4v*)src;
            float4v v1 = *(const float4v*)(src + 4);
            half8 hv;
#pragma unroll
            for (int q = 0; q < 4; ++q) { hv[q] = (_Float16)v0[q]; hv[4 + q] = (_Float16)v1[q]; }
            *(half8*)(&As[c * 8]) = hv;
        }
#pragma unroll
        for (int it = 0; it < 4; ++it) {
            int c = it * 256 + tid;
            const _Float16* src = w16 + (n0 + (c >> 3)) * (long)EMBD + kt * 64 + (c & 7) * 8;
            *(half8*)(&Bs[c * 8]) = *(const half8*)src;
        }
        __syncthreads();
#pragma unroll
        for (int kk = 0; kk < 2; ++kk) {
            half8 a[4], b[4];
#pragma unroll
            for (int m = 0; m < 4; ++m)
                a[m] = *(half8*)(&As[(wr + m * 16 + ln15) * 64 + kk * 32 + kg * 8]);
#pragma unroll
            for (int n = 0; n < 4; ++n)
                b[n] = *(half8*)(&Bs[(wc + n * 16 + ln15) * 64 + kk * 32 + kg * 8]);
#pragma unroll
            for (int m = 0; m < 4; ++m)
#pragma unroll
                for (int n = 0; n < 4; ++n)
                    acc[m][n] = __builtin_amdgcn_mfma_f32_16x16x32_f16(a[m], b[n], acc[m][n], 0, 0, 0);
        }
    }
#pragma unroll
    for (int n = 0; n < 4; ++n) {
        int j = wc + n * 16 + ln15;
        float bv = bias[n0 + j];
#pragma unroll
        for (int m = 0; m < 4; ++m)
#pragma unroll
            for (int r = 0; r < 4; ++r) {
                int i = wr + m * 16 + kg * 4 + r;
                xproj[(m0 + i) * (long)HID + n0 + j] = (_Float16)(acc[m][n][r] + bv);
            }
    }
}

// ---------------- Phase B: persistent scan, 4 independent row-groups ----------------
// 256 blocks: gid = bx&3 owns batch rows [32*gid, 32*gid+32); sub = bx>>2 owns cols
// [32*sub, 32*sub+32). W slice (32 cols x 2048 K, 128 KB) lives in LDS, XOR-swizzled.
// Groups are data-disjoint -> per-group 64-block barrier only.
__global__ __launch_bounds__(256, 1) void scan_kernel(const _Float16* __restrict__ xproj,
                                                      const _Float16* __restrict__ whh,
                                                      _Float16* __restrict__ hA,
                                                      _Float16* __restrict__ hB,
                                                      float* __restrict__ hlast,
                                                      unsigned* __restrict__ cnt) {
    __shared__ __align__(16) _Float16 Wl[32 * 2048];   // 128 KB
    __shared__ __align__(16) float part[4 * 32 * 36];  // 18 KB, padded stride 36

    const int tid = threadIdx.x;
    const int bx = blockIdx.x;
    const int gid = bx & 3;
    const int sub = bx >> 2;
    const int m0 = gid * 32;
    const int n0 = sub * 32;
    const int lane = tid & 63, w = tid >> 6;
    const int ln15 = lane & 15, kg = lane >> 4;
    const int kbase = w * 512;  // per-wave K slice

    // ---- stage W[n0..n0+32)[0..2048) into LDS, swizzled: byte = col*4096 + (k2 ^ ((col&7)<<4))
    for (int it = 0; it < 32; ++it) {
        int c = it * 256 + tid;           // 8192 chunks of 8 elems
        int col = c >> 8;                 // 0..31
        int ch = c & 255;                 // k-chunk
        half8 v = *(const half8*)(whh + (long)(n0 + col) * HID + ch * 8);
        *(half8*)((char*)Wl + col * 4096 + ((ch * 16) ^ ((col & 7) << 4))) = v;
    }
    __syncthreads();

    unsigned* grpCnt  = cnt + gid * 32;        // one cacheline per group counter
    unsigned* grpFlag = cnt + (4 + gid) * 32;  // one cacheline per group flag
    const int redI = tid >> 3;                 // 0..31 output row
    const int redJ = (tid & 7) * 4;            // 0..28 output col base
    const int swzm = (ln15 & 7) << 4;

    for (int t = 0; t < TSTEPS; ++t) {
        const _Float16* hcur = (t & 1) ? hB : hA;
        _Float16* hnext = (t & 1) ? hA : hB;

        // prefetch xproj early: HBM latency hides under MFMA loop
        half4v xpv = *(const half4v*)(xproj + ((long)t * BATCH + m0 + redI) * HID + n0 + redJ);

        float4v acc[2][2];
#pragma unroll
        for (int mf = 0; mf < 2; ++mf)
#pragma unroll
            for (int nf = 0; nf < 2; ++nf) acc[mf][nf] = (float4v){0.f, 0.f, 0.f, 0.f};

#pragma unroll
        for (int ki = 0; ki < 16; ++ki) {
            const _Float16* ap = hcur + (long)(m0 + ln15) * HID + kbase + ki * 32 + kg * 8;
            half8 a0 = *(const half8*)ap;
            half8 a1 = *(const half8*)(ap + 16 * HID);
            int k2 = kbase * 2 + kg * 16 + ki * 64;  // byte offset within a W row, < 4096
            half8 b0 = *(half8*)((char*)Wl + ln15 * 4096        + (k2 ^ swzm));
            half8 b1 = *(half8*)((char*)Wl + (16 + ln15) * 4096 + (k2 ^ swzm));
            acc[0][0] = __builtin_amdgcn_mfma_f32_16x16x32_f16(a0, b0, acc[0][0], 0, 0, 0);
            acc[0][1] = __builtin_amdgcn_mfma_f32_16x16x32_f16(a0, b1, acc[0][1], 0, 0, 0);
            acc[1][0] = __builtin_amdgcn_mfma_f32_16x16x32_f16(a1, b0, acc[1][0], 0, 0, 0);
            acc[1][1] = __builtin_amdgcn_mfma_f32_16x16x32_f16(a1, b1, acc[1][1], 0, 0, 0);
        }

        // partial K-sums to LDS (stride 36 pads kg groups onto disjoint banks)
#pragma unroll
        for (int mf = 0; mf < 2; ++mf)
#pragma unroll
            for (int nf = 0; nf < 2; ++nf)
#pragma unroll
                for (int r = 0; r < 4; ++r) {
                    int i = mf * 16 + kg * 4 + r, j = nf * 16 + ln15;
                    part[w * 1152 + i * 36 + j] = acc[mf][nf][r];
                }
        __syncthreads();

        // reduce across 4 K-slices + bias(xproj) + tanh + store h
        float4v s = *(float4v*)(&part[redI * 36 + redJ]);
#pragma unroll
        for (int ww = 1; ww < 4; ++ww)
            s = s + *(float4v*)(&part[ww * 1152 + redI * 36 + redJ]);
        float o0 = tanhf(s[0] + (float)xpv[0]);
        float o1 = tanhf(s[1] + (float)xpv[1]);
        float o2 = tanhf(s[2] + (float)xpv[2]);
        float o3 = tanhf(s[3] + (float)xpv[3]);
        half4v hv; hv[0] = (_Float16)o0; hv[1] = (_Float16)o1; hv[2] = (_Float16)o2; hv[3] = (_Float16)o3;
        long hoff = (long)(m0 + redI) * HID + n0 + redJ;
        *(half4v*)(hnext + hoff) = hv;
        if (t == TSTEPS - 1) {
            float4v f = {o0, o1, o2, o3};
            *(float4v*)(hlast + hoff) = f;
        }

        // ---- group barrier: 1 release-add per block; last arriver release-stores flag;
        // pollers acquire-poll the flag (single writer -> no invalidation storm).
        __syncthreads();
        if (tid == 0) {
            unsigned old = __hip_atomic_fetch_add(grpCnt, 1u, __ATOMIC_RELEASE, __HIP_MEMORY_SCOPE_AGENT);
            if (old == (unsigned)t * 64u + 63u)
                __hip_atomic_store(grpFlag, (unsigned)(t + 1), __ATOMIC_RELEASE, __HIP_MEMORY_SCOPE_AGENT);
            while (__hip_atomic_load(grpFlag, __ATOMIC_ACQUIRE, __HIP_MEMORY_SCOPE_AGENT) < (unsigned)(t + 1))
                __builtin_amdgcn_s_sleep(2);
        }
        __syncthreads();
    }
}

// ---------------- head ----------------
__global__ __launch_bounds__(256) void fc1_kernel(const float* __restrict__ hlast,
                                                  const float* __restrict__ w,
                                                  const float* __restrict__ b,
                                                  float* __restrict__ z) {
    int bb = blockIdx.x;
    int j = threadIdx.x;
    const float* hr = hlast + (long)bb * HID;
    const float* wr = w + (long)j * HID;
    float acc = 0.f;
    for (int k = 0; k < HID; k += 4) {
        float4v hv = *(const float4v*)(hr + k);
        float4v wv = *(const float4v*)(wr + k);
        acc += hv[0] * wv[0] + hv[1] * wv[1] + hv[2] * wv[2] + hv[3] * wv[3];
    }
    acc += b[j];
    z[bb * 256 + j] = fmaxf(acc, 0.f);
}

__global__ __launch_bounds__(256) void fc2_kernel(const float* __restrict__ z,
                                                  const float* __restrict__ w,
                                                  const float* __restrict__ b,
                                                  float* __restrict__ out) {
    __shared__ float red[4];
    int bb = blockIdx.x;
    int tid = threadIdx.x;
    float zv = z[bb * 256 + tid];
    for (int c = 0; c < 3; ++c) {
        float s = zv * w[c * 256 + tid];
        for (int off = 32; off > 0; off >>= 1) s += __shfl_down(s, off, 64);
        if ((tid & 63) == 0) red[tid >> 6] = s;
        __syncthreads();
        if (tid == 0) out[bb * 3 + c] = red[0] + red[1] + red[2] + red[3] + b[c];
        __syncthreads();
    }
}

// ---------------- launch ----------------
extern "C" void kernel_launch(void* const* d_in, const int* in_sizes, int n_in,
                              void* d_out, int out_size, void* d_ws, size_t ws_size,
                              hipStream_t stream) {
    const int*   x    = (const int*)d_in[0];
    const float* emb  = (const float*)d_in[1];
    const float* Wih  = (const float*)d_in[2];
    const float* Whh  = (const float*)d_in[3];
    const float* bih  = (const float*)d_in[4];
    const float* bhh  = (const float*)d_in[5];
    const float* fc1w = (const float*)d_in[6];
    const float* fc1b = (const float*)d_in[7];
    const float* fc2w = (const float*)d_in[8];
    const float* fc2b = (const float*)d_in[9];
    float* out = (float*)d_out;

    char* ws = (char*)d_ws;
    size_t off = 0;
    _Float16* xproj = (_Float16*)(ws + off); off += (size_t)TSTEPS * BATCH * HID * 2;  // 134.2 MB
    _Float16* wih16 = (_Float16*)(ws + off); off += (size_t)HID * EMBD * 2;            // 8 MB
    _Float16* whh16 = (_Float16*)(ws + off); off += (size_t)HID * HID * 2;             // 8 MB
    float*    bias  = (float*)(ws + off);    off += (size_t)HID * 4;
    _Float16* hA    = (_Float16*)(ws + off); off += (size_t)BATCH * HID * 2;
    _Float16* hB    = (_Float16*)(ws + off); off += (size_t)BATCH * HID * 2;
    float*    hlast = (float*)(ws + off);    off += (size_t)BATCH * HID * 4;
    float*    z     = (float*)(ws + off);    off += (size_t)BATCH * 256 * 4;
    unsigned* cnt   = (unsigned*)(ws + off); off += 2048;

    hipMemsetAsync(cnt, 0, 2048, stream);
    hipMemsetAsync(hA, 0, (size_t)BATCH * HID * 2, stream);

    cast_f16_kernel<<<4096, 256, 0, stream>>>(Wih, wih16, HID * EMBD);
    cast_f16_kernel<<<4096, 256, 0, stream>>>(Whh, whh16, HID * HID);
    bias_kernel<<<8, 256, 0, stream>>>(bih, bhh, bias);

    phaseA_kernel<<<4096, 256, 0, stream>>>(x, emb, wih16, bias, xproj);

    void* args[] = {(void*)&xproj, (void*)&whh16, (void*)&hA, (void*)&hB, (void*)&hlast, (void*)&cnt};
    hipLaunchCooperativeKernel((const void*)scan_kernel, dim3(256), dim3(256), args, 0, stream);

    fc1_kernel<<<BATCH, 256, 0, stream>>>(hlast, fc1w, fc1b, z);
    fc2_kernel<<<BATCH, 256, 0, stream>>>(z, fc2w, fc2b, out);
}

// Round 3
// 5081.973 us; speedup vs baseline: 2.1632x; 1.0006x over previous
//
#include <hip/hip_runtime.h>

typedef _Float16 half8 __attribute__((ext_vector_type(8)));
typedef _Float16 half4v __attribute__((ext_vector_type(4)));
typedef float float4v __attribute__((ext_vector_type(4)));

#define HID 2048
#define EMBD 2048
#define BATCH 128
#define TSTEPS 256
#define FSTRIDE 16  // dwords between flag slots (one 64B line each)

// ---------------- small prep kernels ----------------
__global__ __launch_bounds__(256) void cast_f16_kernel(const float* __restrict__ src,
                                                       _Float16* __restrict__ dst, int n) {
    int i = (blockIdx.x * 256 + threadIdx.x) * 4;
    int stride = gridDim.x * 256 * 4;
    for (; i < n; i += stride) {
        float4v v = *(const float4v*)(src + i);
        half4v h;
        h[0] = (_Float16)v[0]; h[1] = (_Float16)v[1];
        h[2] = (_Float16)v[2]; h[3] = (_Float16)v[3];
        *(half4v*)(dst + i) = h;
    }
}

__global__ __launch_bounds__(256) void bias_kernel(const float* __restrict__ a,
                                                   const float* __restrict__ b,
                                                   float* __restrict__ dst) {
    int i = blockIdx.x * 256 + threadIdx.x;
    if (i < HID) dst[i] = a[i] + b[i];
}

// ---------------- Phase A: xproj = gather(emb,x) @ W_ih^T + bias ----------------
__global__ __launch_bounds__(256) void phaseA_kernel(const int* __restrict__ x,
                                                     const float* __restrict__ emb,
                                                     const _Float16* __restrict__ w16,
                                                     const float* __restrict__ bias,
                                                     _Float16* __restrict__ xproj) {
    __shared__ __align__(16) _Float16 As[128 * 64];
    __shared__ __align__(16) _Float16 Bs[128 * 64];

    const int tid = threadIdx.x;
    const int bx  = blockIdx.x;
    const int nt = bx & 15, mt = bx >> 4;
    const long m0 = (long)mt * 128;
    const long n0 = (long)nt * 128;
    const int lane = tid & 63, w = tid >> 6;
    const int ln15 = lane & 15, kg = lane >> 4;
    const int wr = (w >> 1) * 64, wc = (w & 1) * 64;

    int xr[4];
#pragma unroll
    for (int it = 0; it < 4; ++it) xr[it] = x[m0 + ((it * 256 + tid) >> 3)];

    float4v acc[4][4];
#pragma unroll
    for (int m = 0; m < 4; ++m)
#pragma unroll
        for (int n = 0; n < 4; ++n) acc[m][n] = (float4v){0.f, 0.f, 0.f, 0.f};

    for (int kt = 0; kt < 32; ++kt) {
        __syncthreads();
#pragma unroll
        for (int it = 0; it < 4; ++it) {
            int c = it * 256 + tid;
            const float* src = emb + (long)xr[it] * EMBD + kt * 64 + (c & 7) * 8;
            float4v v0 = *(const float4v*)src;
            float4v v1 = *(const float4v*)(src + 4);
            half8 hv;
#pragma unroll
            for (int q = 0; q < 4; ++q) { hv[q] = (_Float16)v0[q]; hv[4 + q] = (_Float16)v1[q]; }
            *(half8*)(&As[c * 8]) = hv;
        }
#pragma unroll
        for (int it = 0; it < 4; ++it) {
            int c = it * 256 + tid;
            const _Float16* src = w16 + (n0 + (c >> 3)) * (long)EMBD + kt * 64 + (c & 7) * 8;
            *(half8*)(&Bs[c * 8]) = *(const half8*)src;
        }
        __syncthreads();
#pragma unroll
        for (int kk = 0; kk < 2; ++kk) {
            half8 a[4], b[4];
#pragma unroll
            for (int m = 0; m < 4; ++m)
                a[m] = *(half8*)(&As[(wr + m * 16 + ln15) * 64 + kk * 32 + kg * 8]);
#pragma unroll
            for (int n = 0; n < 4; ++n)
                b[n] = *(half8*)(&Bs[(wc + n * 16 + ln15) * 64 + kk * 32 + kg * 8]);
#pragma unroll
            for (int m = 0; m < 4; ++m)
#pragma unroll
                for (int n = 0; n < 4; ++n)
                    acc[m][n] = __builtin_amdgcn_mfma_f32_16x16x32_f16(a[m], b[n], acc[m][n], 0, 0, 0);
        }
    }
#pragma unroll
    for (int n = 0; n < 4; ++n) {
        int j = wc + n * 16 + ln15;
        float bv = bias[n0 + j];
#pragma unroll
        for (int m = 0; m < 4; ++m)
#pragma unroll
            for (int r = 0; r < 4; ++r) {
                int i = wr + m * 16 + kg * 4 + r;
                xproj[(m0 + i) * (long)HID + n0 + j] = (_Float16)(acc[m][n][r] + bv);
            }
    }
}

// ---------------- Phase B: persistent scan ----------------
// 256 blocks. gid = bx&3 owns batch rows [32*gid,+32); sub = bx>>2 owns cols [32*sub,+32).
// Default XCD mapping (bx%8) puts each group on exactly 2 XCDs, disjoint from other
// groups -> h exchange + poll invalidates stay XCD-pair-local.
// Per block: W slice 32 cols x 2048 K in LDS (128 KB, XOR-swizzled).
// Wave w owns quadrant (qr=w>>1, qc=w&1): 16 rows x 16 cols x full K  -> no
// cross-wave reduce, no part buffer.
// Barrier: arrival = release-store to block's own flag line (no RMW!);
// wave 0 polls all 64 group flags with one vector acquire-load per iteration.
__global__ __launch_bounds__(256, 1) void scan_kernel(const _Float16* __restrict__ xproj,
                                                      const _Float16* __restrict__ whh,
                                                      _Float16* __restrict__ hA,
                                                      _Float16* __restrict__ hB,
                                                      float* __restrict__ hlast,
                                                      unsigned* __restrict__ flags) {
    __shared__ __align__(16) _Float16 Wl[32 * 2048];  // 128 KB

    const int tid = threadIdx.x;
    const int bx = blockIdx.x;
    const int gid = bx & 3;
    const int sub = bx >> 2;
    const int m0 = gid * 32;
    const int n0 = sub * 32;
    const int lane = tid & 63, w = tid >> 6;
    const int ln15 = lane & 15, kg = lane >> 4;
    const int qr = w >> 1, qc = w & 1;

    // stage W[n0..n0+32)x[0..2048) into LDS; byte = col*4096 + (k2 ^ ((col&7)<<4))
    for (int it = 0; it < 32; ++it) {
        int c = it * 256 + tid;
        int col = c >> 8;
        int ch = c & 255;
        half8 v = *(const half8*)(whh + (long)(n0 + col) * HID + ch * 8);
        *(half8*)((char*)Wl + col * 4096 + ((ch * 16) ^ ((col & 7) << 4))) = v;
    }
    __syncthreads();

    unsigned* gflags = flags + gid * 64 * FSTRIDE;
    const int arow = m0 + qr * 16 + ln15;                    // A-operand row for this lane
    const int wcolbyte = (qc * 16 + ln15) * 4096;            // B-operand W row base in LDS
    const int swz = (ln15 & 7) << 4;
    const int orow = m0 + qr * 16 + kg * 4;                  // output rows orow..orow+3
    const int ocol = n0 + qc * 16 + ln15;                    // output col

    for (int t = 0; t < TSTEPS; ++t) {
        const _Float16* hcur = (t & 1) ? hB : hA;
        _Float16* hnext = (t & 1) ? hA : hB;

        // prefetch xproj for this step's 4 output elements (overlaps MFMA loop)
        const _Float16* xp = xproj + (long)t * BATCH * HID;
        _Float16 xpv[4];
#pragma unroll
        for (int r = 0; r < 4; ++r) xpv[r] = xp[(long)(orow + r) * HID + ocol];

        const _Float16* hrow = hcur + (long)arow * HID;
        float4v acc0 = (float4v){0.f, 0.f, 0.f, 0.f};
        float4v acc1 = (float4v){0.f, 0.f, 0.f, 0.f};
#pragma unroll
        for (int ki = 0; ki < 64; ki += 2) {
            half8 a0 = *(const half8*)(hrow + ki * 32 + kg * 8);
            half8 b0 = *(half8*)((char*)Wl + wcolbyte + ((ki * 64 + kg * 16) ^ swz));
            acc0 = __builtin_amdgcn_mfma_f32_16x16x32_f16(a0, b0, acc0, 0, 0, 0);
            half8 a1 = *(const half8*)(hrow + (ki + 1) * 32 + kg * 8);
            half8 b1 = *(half8*)((char*)Wl + wcolbyte + (((ki + 1) * 64 + kg * 16) ^ swz));
            acc1 = __builtin_amdgcn_mfma_f32_16x16x32_f16(a1, b1, acc1, 0, 0, 0);
        }

        // epilogue: 4 output elements per lane (rows orow+r, col ocol)
#pragma unroll
        for (int r = 0; r < 4; ++r) {
            float o = tanhf(acc0[r] + acc1[r] + (float)xpv[r]);
            hnext[(long)(orow + r) * HID + ocol] = (_Float16)o;
            if (t == TSTEPS - 1) hlast[(long)(orow + r) * HID + ocol] = o;
        }
        if (t == TSTEPS - 1) break;  // no barrier needed after last step

        // ---- group barrier: release-store own flag line; wave0 polls all 64 flags
        __syncthreads();
        if (tid == 0)
            __hip_atomic_store(&gflags[sub * FSTRIDE], (unsigned)(t + 1),
                               __ATOMIC_RELEASE, __HIP_MEMORY_SCOPE_AGENT);
        if (tid < 64) {
            for (;;) {
                unsigned v = __hip_atomic_load(&gflags[tid * FSTRIDE],
                                               __ATOMIC_ACQUIRE, __HIP_MEMORY_SCOPE_AGENT);
                if (__all(v > (unsigned)t)) break;
                __builtin_amdgcn_s_sleep(1);
            }
        }
        __syncthreads();
    }
}

// ---------------- head ----------------
__global__ __launch_bounds__(256) void fc1_kernel(const float* __restrict__ hlast,
                                                  const float* __restrict__ w,
                                                  const float* __restrict__ b,
                                                  float* __restrict__ z) {
    int bb = blockIdx.x;
    int j = threadIdx.x;
    const float* hr = hlast + (long)bb * HID;
    const float* wr = w + (long)j * HID;
    float acc = 0.f;
    for (int k = 0; k < HID; k += 4) {
        float4v hv = *(const float4v*)(hr + k);
        float4v wv = *(const float4v*)(wr + k);
        acc += hv[0] * wv[0] + hv[1] * wv[1] + hv[2] * wv[2] + hv[3] * wv[3];
    }
    acc += b[j];
    z[bb * 256 + j] = fmaxf(acc, 0.f);
}

__global__ __launch_bounds__(256) void fc2_kernel(const float* __restrict__ z,
                                                  const float* __restrict__ w,
                                                  const float* __restrict__ b,
                                                  float* __restrict__ out) {
    __shared__ float red[4];
    int bb = blockIdx.x;
    int tid = threadIdx.x;
    float zv = z[bb * 256 + tid];
    for (int c = 0; c < 3; ++c) {
        float s = zv * w[c * 256 + tid];
        for (int off = 32; off > 0; off >>= 1) s += __shfl_down(s, off, 64);
        if ((tid & 63) == 0) red[tid >> 6] = s;
        __syncthreads();
        if (tid == 0) out[bb * 3 + c] = red[0] + red[1] + red[2] + red[3] + b[c];
        __syncthreads();
    }
}

// ---------------- launch ----------------
extern "C" void kernel_launch(void* const* d_in, const int* in_sizes, int n_in,
                              void* d_out, int out_size, void* d_ws, size_t ws_size,
                              hipStream_t stream) {
    const int*   x    = (const int*)d_in[0];
    const float* emb  = (const float*)d_in[1];
    const float* Wih  = (const float*)d_in[2];
    const float* Whh  = (const float*)d_in[3];
    const float* bih  = (const float*)d_in[4];
    const float* bhh  = (const float*)d_in[5];
    const float* fc1w = (const float*)d_in[6];
    const float* fc1b = (const float*)d_in[7];
    const float* fc2w = (const float*)d_in[8];
    const float* fc2b = (const float*)d_in[9];
    float* out = (float*)d_out;

    char* ws = (char*)d_ws;
    size_t off = 0;
    _Float16* xproj = (_Float16*)(ws + off); off += (size_t)TSTEPS * BATCH * HID * 2;  // 134.2 MB
    _Float16* wih16 = (_Float16*)(ws + off); off += (size_t)HID * EMBD * 2;            // 8 MB
    _Float16* whh16 = (_Float16*)(ws + off); off += (size_t)HID * HID * 2;             // 8 MB
    float*    bias  = (float*)(ws + off);    off += (size_t)HID * 4;
    _Float16* hA    = (_Float16*)(ws + off); off += (size_t)BATCH * HID * 2;
    _Float16* hB    = (_Float16*)(ws + off); off += (size_t)BATCH * HID * 2;
    float*    hlast = (float*)(ws + off);    off += (size_t)BATCH * HID * 4;
    float*    z     = (float*)(ws + off);    off += (size_t)BATCH * 256 * 4;
    unsigned* flags = (unsigned*)(ws + off); off += 4 * 64 * FSTRIDE * 4;  // 16 KB

    hipMemsetAsync(flags, 0, 4 * 64 * FSTRIDE * 4, stream);
    hipMemsetAsync(hA, 0, (size_t)BATCH * HID * 2, stream);

    cast_f16_kernel<<<4096, 256, 0, stream>>>(Wih, wih16, HID * EMBD);
    cast_f16_kernel<<<4096, 256, 0, stream>>>(Whh, whh16, HID * HID);
    bias_kernel<<<8, 256, 0, stream>>>(bih, bhh, bias);

    phaseA_kernel<<<4096, 256, 0, stream>>>(x, emb, wih16, bias, xproj);

    void* args[] = {(void*)&xproj, (void*)&whh16, (void*)&hA, (void*)&hB, (void*)&hlast, (void*)&flags};
    hipLaunchCooperativeKernel((const void*)scan_kernel, dim3(256), dim3(256), args, 0, stream);

    fc1_kernel<<<BATCH, 256, 0, stream>>>(hlast, fc1w, fc1b, z);
    fc2_kernel<<<BATCH, 256, 0, stream>>>(z, fc2w, fc2b, out);
}

// Round 4
// 2735.341 us; speedup vs baseline: 4.0190x; 1.8579x over previous
//
#include <hip/hip_runtime.h>

typedef _Float16 half8 __attribute__((ext_vector_type(8)));
typedef _Float16 half4v __attribute__((ext_vector_type(4)));
typedef float float4v __attribute__((ext_vector_type(4)));

#define HID 2048
#define EMBD 2048
#define BATCH 128
#define TSTEPS 256
#define STEP ((size_t)BATCH * HID)

// ---------------- small prep kernels ----------------
__global__ __launch_bounds__(256) void cast_f16_kernel(const float* __restrict__ src,
                                                       _Float16* __restrict__ dst, int n) {
    int i = (blockIdx.x * 256 + threadIdx.x) * 4;
    int stride = gridDim.x * 256 * 4;
    for (; i < n; i += stride) {
        float4v v = *(const float4v*)(src + i);
        half4v h;
        h[0] = (_Float16)v[0]; h[1] = (_Float16)v[1];
        h[2] = (_Float16)v[2]; h[3] = (_Float16)v[3];
        *(half4v*)(dst + i) = h;
    }
}

__global__ __launch_bounds__(256) void bias_kernel(const float* __restrict__ a,
                                                   const float* __restrict__ b,
                                                   float* __restrict__ dst) {
    int i = blockIdx.x * 256 + threadIdx.x;
    if (i < HID) dst[i] = a[i] + b[i];
}

// ---------------- Phase A: xproj = gather(emb,x) @ W_ih^T + bias ----------------
// Swapped-operand MFMA: D^T fragment -> lane holds 4 consecutive n-cols -> 8B stores.
__global__ __launch_bounds__(256) void phaseA_kernel(const int* __restrict__ x,
                                                     const float* __restrict__ emb,
                                                     const _Float16* __restrict__ w16,
                                                     const float* __restrict__ bias,
                                                     _Float16* __restrict__ xproj) {
    __shared__ __align__(16) _Float16 As[128 * 64];
    __shared__ __align__(16) _Float16 Bs[128 * 64];

    const int tid = threadIdx.x;
    const int bx  = blockIdx.x;
    const int nt = bx & 15, mt = bx >> 4;
    const long m0 = (long)mt * 128;
    const long n0 = (long)nt * 128;
    const int lane = tid & 63, w = tid >> 6;
    const int ln15 = lane & 15, kg = lane >> 4;
    const int wr = (w >> 1) * 64, wc = (w & 1) * 64;

    int xr[4];
#pragma unroll
    for (int it = 0; it < 4; ++it) xr[it] = x[m0 + ((it * 256 + tid) >> 3)];

    float4v acc[4][4];
#pragma unroll
    for (int m = 0; m < 4; ++m)
#pragma unroll
        for (int n = 0; n < 4; ++n) acc[m][n] = (float4v){0.f, 0.f, 0.f, 0.f};

    for (int kt = 0; kt < 32; ++kt) {
        __syncthreads();
#pragma unroll
        for (int it = 0; it < 4; ++it) {
            int c = it * 256 + tid;
            const float* src = emb + (long)xr[it] * EMBD + kt * 64 + (c & 7) * 8;
            float4v v0 = *(const float4v*)src;
            float4v v1 = *(const float4v*)(src + 4);
            half8 hv;
#pragma unroll
            for (int q = 0; q < 4; ++q) { hv[q] = (_Float16)v0[q]; hv[4 + q] = (_Float16)v1[q]; }
            *(half8*)(&As[c * 8]) = hv;
        }
#pragma unroll
        for (int it = 0; it < 4; ++it) {
            int c = it * 256 + tid;
            const _Float16* src = w16 + (n0 + (c >> 3)) * (long)EMBD + kt * 64 + (c & 7) * 8;
            *(half8*)(&Bs[c * 8]) = *(const half8*)src;
        }
        __syncthreads();
#pragma unroll
        for (int kk = 0; kk < 2; ++kk) {
            half8 a[4], b[4];
#pragma unroll
            for (int m = 0; m < 4; ++m)
                a[m] = *(half8*)(&As[(wr + m * 16 + ln15) * 64 + kk * 32 + kg * 8]);
#pragma unroll
            for (int n = 0; n < 4; ++n)
                b[n] = *(half8*)(&Bs[(wc + n * 16 + ln15) * 64 + kk * 32 + kg * 8]);
            // swapped operands: result is transposed fragment (col=ln15 <-> m-rows)
#pragma unroll
            for (int m = 0; m < 4; ++m)
#pragma unroll
                for (int n = 0; n < 4; ++n)
                    acc[m][n] = __builtin_amdgcn_mfma_f32_16x16x32_f16(b[n], a[m], acc[m][n], 0, 0, 0);
        }
    }
    // epilogue: lane holds rows m = wr+m*16+ln15, cols n = wc+n*16+kg*4 .. +3 (contiguous)
#pragma unroll
    for (int m = 0; m < 4; ++m) {
        long mg = m0 + wr + m * 16 + ln15;
#pragma unroll
        for (int n = 0; n < 4; ++n) {
            int nb = (int)n0 + wc + n * 16 + kg * 4;
            float4v bv = *(const float4v*)(bias + nb);
            union { half4v h; unsigned long long u; } pk;
#pragma unroll
            for (int r = 0; r < 4; ++r) pk.h[r] = (_Float16)(acc[m][n][r] + bv[r]);
            *(unsigned long long*)(xproj + mg * HID + nb) = pk.u;
        }
    }
}

// ---------------- Phase B: persistent scan, zero-cache-maintenance protocol ----------------
// 256 blocks. gid=bx&3 owns batch rows [32*gid,+32); sub=bx>>2 owns cols [32*sub,+32).
// W slice (32 cols x 2048) in LDS. Waves: pair p=w>>1 (rows 16p..+16), khalf=w&1
// (k in [1024*kh, +1024)) -> pairwise K-split, LDS reduce.
// h_{t+1} is written INTO xproj[t] (each element consumed by the same thread earlier
// in the step). h writes + bias reads + flags = relaxed agent atomics (sc1 bypass, NO
// inv/wbl2). A-operand h reads = plain cacheable loads on first-touch addresses.
__global__ __launch_bounds__(256, 1) void scan_kernel(_Float16* __restrict__ xproj,
                                                      const _Float16* __restrict__ whh,
                                                      const _Float16* __restrict__ h0,
                                                      float* __restrict__ hlast,
                                                      unsigned* __restrict__ flags) {
    __shared__ __align__(16) _Float16 Wl[32 * 2048];  // 128 KB
    __shared__ __align__(16) float part[4][16 * 40];  // 10.25 KB

    const int tid = threadIdx.x;
    const int bx = blockIdx.x;
    const int gid = bx & 3;
    const int sub = bx >> 2;
    const int m0 = gid * 32;
    const int n0 = sub * 32;
    const int lane = tid & 63, w = tid >> 6;
    const int ln15 = lane & 15, kg = lane >> 4;
    const int pr = w >> 1;      // row-pair 0/1
    const int kh = w & 1;       // k-half 0/1

    // stage W[n0..n0+32)x[0..2048) into LDS; byte = col*4096 + (k2 ^ ((col&7)<<4))
    for (int it = 0; it < 32; ++it) {
        int c = it * 256 + tid;
        int col = c >> 8;
        int ch = c & 255;
        half8 v = *(const half8*)(whh + (long)(n0 + col) * HID + ch * 8);
        *(half8*)((char*)Wl + col * 4096 + ((ch * 16) ^ ((col & 7) << 4))) = v;
    }
    __syncthreads();

    unsigned* gfl = flags + gid * 64;  // 64 u32 per group (256B, 4 lines)
    // reduce/output mapping: thread -> (pair rp, row rrow, col-quad rc4)
    const int rp = tid >> 7;
    const int ridx = tid & 127;
    const int rrow = ridx >> 3;
    const int rc4 = (ridx & 7) * 4;
    const int grow = m0 + rp * 16 + rrow;   // global batch row
    const int gcol = n0 + rc4;              // global col base (4 wide)

    const int wb0 = ln15 * 4096;            // W LDS row bases
    const int wb1 = (16 + ln15) * 4096;
    const int swz = (ln15 & 7) << 4;
    const int kb = kh * 2048;               // k-half byte offset in W row
    const int arow = m0 + pr * 16 + ln15;   // A-operand row

    for (int t = 0; t < TSTEPS; ++t) {
        const _Float16* hcur = (t == 0) ? h0 : xproj + (size_t)(t - 1) * STEP;
        _Float16* hnext = xproj + (size_t)t * STEP;  // alias: overwrite xproj[t]

        // bias prefetch (bypass 8B atomic; consumed after reduce)
        unsigned long long xbits = __hip_atomic_load(
            (const unsigned long long*)(xproj + (size_t)t * STEP + (size_t)grow * HID + gcol),
            __ATOMIC_RELAXED, __HIP_MEMORY_SCOPE_AGENT);

        // MFMA: rows [m0+16pr,+16) x cols [n0,+32) over k in [1024kh,+1024)
        const _Float16* hrow = hcur + (size_t)arow * HID + kh * 1024;
        float4v acc0 = (float4v){0.f, 0.f, 0.f, 0.f};
        float4v acc1 = (float4v){0.f, 0.f, 0.f, 0.f};
#pragma unroll
        for (int ki = 0; ki < 32; ++ki) {
            half8 a = *(const half8*)(hrow + ki * 32 + kg * 8);
            int k2 = kb + ki * 64 + kg * 16;
            half8 b0 = *(half8*)((char*)Wl + wb0 + (k2 ^ swz));
            half8 b1 = *(half8*)((char*)Wl + wb1 + (k2 ^ swz));
            acc0 = __builtin_amdgcn_mfma_f32_16x16x32_f16(a, b0, acc0, 0, 0, 0);
            acc1 = __builtin_amdgcn_mfma_f32_16x16x32_f16(a, b1, acc1, 0, 0, 0);
        }

        // partial K-sums to LDS: lane (kg,ln15) holds rows kg*4+r, col nf*16+ln15
#pragma unroll
        for (int r = 0; r < 4; ++r) {
            part[w][(kg * 4 + r) * 40 + ln15] = acc0[r];
            part[w][(kg * 4 + r) * 40 + 16 + ln15] = acc1[r];
        }
        __syncthreads();

        // reduce pair of k-halves + bias + tanh + packed 8B bypass store
        float4v s = *(const float4v*)(&part[2 * rp][rrow * 40 + rc4]) +
                    *(const float4v*)(&part[2 * rp + 1][rrow * 40 + rc4]);
        union { unsigned long long u; half4v h; } xb; xb.u = xbits;
        float o0 = tanhf(s[0] + (float)xb.h[0]);
        float o1 = tanhf(s[1] + (float)xb.h[1]);
        float o2 = tanhf(s[2] + (float)xb.h[2]);
        float o3 = tanhf(s[3] + (float)xb.h[3]);
        union { half4v h; unsigned long long u; } pk;
        pk.h[0] = (_Float16)o0; pk.h[1] = (_Float16)o1;
        pk.h[2] = (_Float16)o2; pk.h[3] = (_Float16)o3;
        __hip_atomic_store((unsigned long long*)(hnext + (size_t)grow * HID + gcol), pk.u,
                           __ATOMIC_RELAXED, __HIP_MEMORY_SCOPE_AGENT);
        if (t == TSTEPS - 1) {
            float4v f = {o0, o1, o2, o3};
            *(float4v*)(hlast + (size_t)grow * HID + gcol) = f;
            break;  // last step: no barrier
        }

        // ---- group barrier, all relaxed (no inv/wbl2 anywhere) ----
        // syncthreads drains each thread's vmcnt => all h stores are at L3.
        __syncthreads();
        if (tid == 0)
            __hip_atomic_store(&gfl[sub], (unsigned)(t + 1),
                               __ATOMIC_RELAXED, __HIP_MEMORY_SCOPE_AGENT);
        if (tid < 32) {
            const unsigned long long* pp = (const unsigned long long*)gfl + tid;
            for (;;) {
                unsigned long long v = __hip_atomic_load(pp, __ATOMIC_RELAXED,
                                                         __HIP_MEMORY_SCOPE_AGENT);
                bool ok = ((unsigned)v > (unsigned)t) && ((unsigned)(v >> 32) > (unsigned)t);
                if (__all(ok)) break;
                __builtin_amdgcn_s_sleep(2);
            }
        }
        __syncthreads();
    }
}

// ---------------- head ----------------
__global__ __launch_bounds__(256) void fc1_kernel(const float* __restrict__ hlast,
                                                  const float* __restrict__ w,
                                                  const float* __restrict__ b,
                                                  float* __restrict__ z) {
    int bb = blockIdx.x;
    int j = threadIdx.x;
    const float* hr = hlast + (long)bb * HID;
    const float* wr = w + (long)j * HID;
    float acc = 0.f;
    for (int k = 0; k < HID; k += 4) {
        float4v hv = *(const float4v*)(hr + k);
        float4v wv = *(const float4v*)(wr + k);
        acc += hv[0] * wv[0] + hv[1] * wv[1] + hv[2] * wv[2] + hv[3] * wv[3];
    }
    acc += b[j];
    z[bb * 256 + j] = fmaxf(acc, 0.f);
}

__global__ __launch_bounds__(256) void fc2_kernel(const float* __restrict__ z,
                                                  const float* __restrict__ w,
                                                  const float* __restrict__ b,
                                                  float* __restrict__ out) {
    __shared__ float red[4];
    int bb = blockIdx.x;
    int tid = threadIdx.x;
    float zv = z[bb * 256 + tid];
    for (int c = 0; c < 3; ++c) {
        float s = zv * w[c * 256 + tid];
        for (int off = 32; off > 0; off >>= 1) s += __shfl_down(s, off, 64);
        if ((tid & 63) == 0) red[tid >> 6] = s;
        __syncthreads();
        if (tid == 0) out[bb * 3 + c] = red[0] + red[1] + red[2] + red[3] + b[c];
        __syncthreads();
    }
}

// ---------------- launch ----------------
extern "C" void kernel_launch(void* const* d_in, const int* in_sizes, int n_in,
                              void* d_out, int out_size, void* d_ws, size_t ws_size,
                              hipStream_t stream) {
    const int*   x    = (const int*)d_in[0];
    const float* emb  = (const float*)d_in[1];
    const float* Wih  = (const float*)d_in[2];
    const float* Whh  = (const float*)d_in[3];
    const float* bih  = (const float*)d_in[4];
    const float* bhh  = (const float*)d_in[5];
    const float* fc1w = (const float*)d_in[6];
    const float* fc1b = (const float*)d_in[7];
    const float* fc2w = (const float*)d_in[8];
    const float* fc2b = (const float*)d_in[9];
    float* out = (float*)d_out;

    char* ws = (char*)d_ws;
    size_t off = 0;
    _Float16* xproj = (_Float16*)(ws + off); off += (size_t)TSTEPS * BATCH * HID * 2;  // 134.2 MB
    _Float16* wih16 = (_Float16*)(ws + off); off += (size_t)HID * EMBD * 2;            // 8 MB
    _Float16* whh16 = (_Float16*)(ws + off); off += (size_t)HID * HID * 2;             // 8 MB
    float*    bias  = (float*)(ws + off);    off += (size_t)HID * 4;
    _Float16* h0    = (_Float16*)(ws + off); off += (size_t)BATCH * HID * 2;
    float*    hlast = (float*)(ws + off);    off += (size_t)BATCH * HID * 4;
    float*    z     = (float*)(ws + off);    off += (size_t)BATCH * 256 * 4;
    unsigned* flags = (unsigned*)(ws + off); off += 4 * 64 * 4;  // 1 KB

    hipMemsetAsync(flags, 0, 4 * 64 * 4, stream);
    hipMemsetAsync(h0, 0, (size_t)BATCH * HID * 2, stream);

    cast_f16_kernel<<<4096, 256, 0, stream>>>(Wih, wih16, HID * EMBD);
    cast_f16_kernel<<<4096, 256, 0, stream>>>(Whh, whh16, HID * HID);
    bias_kernel<<<8, 256, 0, stream>>>(bih, bhh, bias);

    phaseA_kernel<<<4096, 256, 0, stream>>>(x, emb, wih16, bias, xproj);

    void* args[] = {(void*)&xproj, (void*)&whh16, (void*)&h0, (void*)&hlast, (void*)&flags};
    hipLaunchCooperativeKernel((const void*)scan_kernel, dim3(256), dim3(256), args, 0, stream);

    fc1_kernel<<<BATCH, 256, 0, stream>>>(hlast, fc1w, fc1b, z);
    fc2_kernel<<<BATCH, 256, 0, stream>>>(z, fc2w, fc2b, out);
}